// Round 1
// baseline (741.112 us; speedup 1.0000x reference)
//
#include <hip/hip_runtime.h>
#include <stdint.h>

typedef unsigned short u16;
typedef __attribute__((ext_vector_type(8))) short short8;
typedef __attribute__((ext_vector_type(4))) float f32x4;

#define MFMA_BF16(a,b,c) __builtin_amdgcn_mfma_f32_16x16x32_bf16((a),(b),(c),0,0,0)

__device__ __forceinline__ u16 f2bf(float x) {
    uint32_t u = __builtin_bit_cast(uint32_t, x);
    u += 0x7fffu + ((u >> 16) & 1u);   // RNE
    return (u16)(u >> 16);
}
__device__ __forceinline__ float bf2f(u16 u) {
    return __builtin_bit_cast(float, (uint32_t)u << 16);
}
// async global->LDS, 16B per lane; LDS dest = wave-uniform base + lane*16
__device__ __forceinline__ void glds16(const void* g, void* lds) {
    __builtin_amdgcn_global_load_lds((const __attribute__((address_space(1))) void*)g,
                                     (__attribute__((address_space(3))) void*)lds,
                                     16, 0, 0);
}

// ---------------- fp32 -> bf16 convert ----------------
__global__ __launch_bounds__(256) void cvt_kernel(const float* __restrict__ src,
                                                  u16* __restrict__ dst, int n) {
    int i = (blockIdx.x * 256 + threadIdx.x) * 4;
    if (i + 4 <= n) {
        float4 v = *(const float4*)(src + i);
        ushort4 o;
        o.x = f2bf(v.x); o.y = f2bf(v.y); o.z = f2bf(v.z); o.w = f2bf(v.w);
        *(ushort4*)(dst + i) = o;
    }
}

// ---------------- GEMM: C[M,N] = A[M,K] * B[N,K]^T (bf16 in, fp32 acc) ----
// 128x128 tile, BK=32, 4 waves each 64x64. XOR-swizzled LDS (2-way reads).
template<bool BF16_OUT>
__global__ __launch_bounds__(256) void gemm_bt(const u16* __restrict__ A,
                                               const u16* __restrict__ B,
                                               void* __restrict__ Cv,
                                               int K, int lda, int ldb, int ldc)
{
    __shared__ __align__(16) u16 As[128 * 32];
    __shared__ __align__(16) u16 Bs[128 * 32];
    const int t = threadIdx.x;
    const int w = t >> 6, l = t & 63;
    const int m0 = blockIdx.y * 128, n0 = blockIdx.x * 128;
    const int wm = (w & 1) * 64, wn = (w >> 1) * 64;
    const int lrow = l & 15, lk = l >> 4;

    f32x4 acc[4][4];
#pragma unroll
    for (int i = 0; i < 4; i++)
#pragma unroll
        for (int j = 0; j < 4; j++) acc[i][j] = (f32x4){0.f, 0.f, 0.f, 0.f};

    // staging: 512 chunks of 16B per tile; chunk c -> row c>>2, slot c&3,
    // LDS slot s holds global chunk s ^ ((row>>1)&3)
    const int c0 = t, c1 = t + 256;
    const int r0 = c0 >> 2, g0 = (c0 & 3) ^ ((r0 >> 1) & 3);
    const int r1 = c1 >> 2, g1 = (c1 & 3) ^ ((r1 >> 1) & 3);
    const u16* Ap0 = A + (size_t)(m0 + r0) * lda + g0 * 8;
    const u16* Ap1 = A + (size_t)(m0 + r1) * lda + g1 * 8;
    const u16* Bp0 = B + (size_t)(n0 + r0) * ldb + g0 * 8;
    const u16* Bp1 = B + (size_t)(n0 + r1) * ldb + g1 * 8;
    char* Asb = (char*)As + w * 1024;
    char* Bsb = (char*)Bs + w * 1024;

    for (int k0 = 0; k0 < K; k0 += 32) {
        __syncthreads();
        glds16(Ap0 + k0, Asb);
        glds16(Ap1 + k0, Asb + 4096);
        glds16(Bp0 + k0, Bsb);
        glds16(Bp1 + k0, Bsb + 4096);
        __syncthreads();
        short8 af[4], bf[4];
#pragma unroll
        for (int mi = 0; mi < 4; mi++) {
            int r = wm + mi * 16 + lrow;
            int sl = lk ^ ((r >> 1) & 3);
            af[mi] = *(const short8*)&As[r * 32 + sl * 8];
        }
#pragma unroll
        for (int ni = 0; ni < 4; ni++) {
            int r = wn + ni * 16 + lrow;
            int sl = lk ^ ((r >> 1) & 3);
            bf[ni] = *(const short8*)&Bs[r * 32 + sl * 8];
        }
#pragma unroll
        for (int mi = 0; mi < 4; mi++)
#pragma unroll
            for (int ni = 0; ni < 4; ni++)
                acc[mi][ni] = MFMA_BF16(af[mi], bf[ni], acc[mi][ni]);
    }

    // C/D layout: col = l&15, row = (l>>4)*4 + reg
#pragma unroll
    for (int mi = 0; mi < 4; mi++) {
#pragma unroll
        for (int r = 0; r < 4; r++) {
            int row = m0 + wm + mi * 16 + lk * 4 + r;
#pragma unroll
            for (int ni = 0; ni < 4; ni++) {
                int col = n0 + wn + ni * 16 + lrow;
                float v = acc[mi][ni][r];
                if (BF16_OUT) ((u16*)Cv)[(size_t)row * ldc + col] = f2bf(v);
                else          ((float*)Cv)[(size_t)row * ldc + col] = v;
            }
        }
    }
}

// ---------------- RMSNorm + RoPE + scatter to attention layouts -----------
// qkv_b: (4096 tokens, 6144) bf16. Row group hd: 0..31 q, 32..39 k, 40..47 v.
// One wave per (token, hd); lane l handles d=l and d=l+64 (RoPE pairing).
__global__ __launch_bounds__(256) void norm_rope(const u16* __restrict__ qkv,
        const float* __restrict__ cosb, const float* __restrict__ sinb,
        const float* __restrict__ qg, const float* __restrict__ kg,
        u16* __restrict__ qb, u16* __restrict__ kb, u16* __restrict__ vtb,
        float* __restrict__ k_out, float* __restrict__ v_out)
{
    const int idx = blockIdx.x * 4 + (threadIdx.x >> 6);
    const int l = threadIdx.x & 63;
    const int tok = idx / 48, hd = idx - tok * 48;
    const int b = tok >> 11, pos = tok & 2047;
    const u16* row = qkv + (size_t)tok * 6144 + hd * 128;
    float x1 = bf2f(row[l]), x2 = bf2f(row[l + 64]);
    float ss = x1 * x1 + x2 * x2;
#pragma unroll
    for (int m = 1; m < 64; m <<= 1) ss += __shfl_xor(ss, m, 64);
    float rn = rsqrtf(ss * (1.0f / 128.0f) + 1e-6f);

    if (hd < 40) {
        const float* gm = (hd < 32) ? qg : kg;
        float xn1 = x1 * rn * gm[l];
        float xn2 = x2 * rn * gm[l + 64];
        float c1 = cosb[(size_t)tok * 128 + l],      s1 = sinb[(size_t)tok * 128 + l];
        float c2 = cosb[(size_t)tok * 128 + l + 64], s2 = sinb[(size_t)tok * 128 + l + 64];
        float y1 = xn1 * c1 - xn2 * s1;   // rotate_half: first half gets -x2
        float y2 = xn2 * c2 + xn1 * s2;
        if (hd < 32) {
            const float qs = 0.08838834764831845f;  // 1/sqrt(128) folded into q
            size_t base = (((size_t)b * 32 + hd) * 2048 + pos) * 128;
            qb[base + l]      = f2bf(y1 * qs);
            qb[base + l + 64] = f2bf(y2 * qs);
        } else {
            int kv = hd - 32;
            size_t base = (((size_t)b * 8 + kv) * 2048 + pos) * 128;
            k_out[base + l] = y1; k_out[base + l + 64] = y2;
            kb[base + l] = f2bf(y1); kb[base + l + 64] = f2bf(y2);
        }
    } else {
        int kv = hd - 40;
        size_t base = (((size_t)b * 8 + kv) * 2048 + pos) * 128;
        v_out[base + l] = x1; v_out[base + l + 64] = x2;
        size_t tbase = ((size_t)b * 8 + kv) * 128;     // V^T: (b,kv,D,s)
        vtb[(tbase + l) * 2048 + pos]      = f2bf(x1);
        vtb[(tbase + l + 64) * 2048 + pos] = f2bf(x2);
    }
}

// ---------------- Flash attention (causal, GQA) ---------------------------
// Block: one (b,h) and a 64-row Q tile; 4 waves x 16 q-rows. KV tile = 64.
__global__ __launch_bounds__(256) void attn_kernel(const u16* __restrict__ qb,
        const u16* __restrict__ kb, const u16* __restrict__ vtb,
        u16* __restrict__ ao)
{
    __shared__ __align__(16) u16 Ks[64 * 128];    // (kv,d) swizzled
    __shared__ __align__(16) u16 Vs[128 * 64];    // (d,kv) swizzled
    __shared__ __align__(16) u16 Ps[4][16 * 72];  // per-wave P, stride 72

    const int bh = blockIdx.x;
    const int b = bh >> 5, h = bh & 31;
    const int kvh = h >> 2;
    const int qt = blockIdx.y;
    const int q0 = qt * 64;
    const int t = threadIdx.x, w = t >> 6, l = t & 63;
    const int lrow = l & 15, lk = l >> 4;

    const u16* qbase  = qb  + ((size_t)b * 32 + h)  * 2048 * 128;
    const u16* kbase  = kb  + ((size_t)b * 8 + kvh) * 2048 * 128;
    const u16* vtbase = vtb + ((size_t)b * 8 + kvh) * 128 * 2048;

    short8 qf[4];   // A-frags for 16 q-rows of this wave, k=d in 4 chunks of 32
    {
        const u16* qrow = qbase + (size_t)(q0 + w * 16 + lrow) * 128 + lk * 8;
#pragma unroll
        for (int ks = 0; ks < 4; ks++) qf[ks] = *(const short8*)(qrow + ks * 32);
    }

    f32x4 o[8];
#pragma unroll
    for (int i = 0; i < 8; i++) o[i] = (f32x4){0.f, 0.f, 0.f, 0.f};
    float mprev[4], lsum[4];
#pragma unroll
    for (int r = 0; r < 4; r++) { mprev[r] = -1e30f; lsum[r] = 0.f; }

    int kR[4], kG[4], vR[4], vG[4];
#pragma unroll
    for (int i = 0; i < 4; i++) {
        int c = i * 256 + t;
        kR[i] = c >> 4; kG[i] = (c & 15) ^ (kR[i] & 7);
        vR[i] = c >> 3; vG[i] = (c & 7)  ^ (vR[i] & 7);
    }
    char* Ksb = (char*)Ks + w * 1024;
    char* Vsb = (char*)Vs + w * 1024;
    u16* pw = &Ps[w][0];

    for (int kt = 0; kt <= qt; kt++) {
        const int kv0 = kt * 64;
        __syncthreads();
#pragma unroll
        for (int i = 0; i < 4; i++)
            glds16(kbase + (size_t)(kv0 + kR[i]) * 128 + kG[i] * 8, Ksb + i * 4096);
#pragma unroll
        for (int i = 0; i < 4; i++)
            glds16(vtbase + (size_t)vR[i] * 2048 + kv0 + vG[i] * 8, Vsb + i * 4096);
        __syncthreads();

        // S = Q K^T (q pre-scaled)
        f32x4 s[4];
#pragma unroll
        for (int i = 0; i < 4; i++) s[i] = (f32x4){0.f, 0.f, 0.f, 0.f};
#pragma unroll
        for (int ks = 0; ks < 4; ks++) {
#pragma unroll
            for (int nt = 0; nt < 4; nt++) {
                int r = nt * 16 + lrow;
                int sl = (ks * 4 + lk) ^ (r & 7);
                short8 kf = *(const short8*)&Ks[r * 128 + sl * 8];
                s[nt] = MFMA_BF16(qf[ks], kf, s[nt]);
            }
        }

        if (kt == qt) {   // causal mask only on diagonal tile
#pragma unroll
            for (int nt = 0; nt < 4; nt++) {
                int cg = kv0 + nt * 16 + lrow;
#pragma unroll
                for (int r = 0; r < 4; r++) {
                    int rg = q0 + w * 16 + lk * 4 + r;
                    if (cg > rg) s[nt][r] = -1e30f;
                }
            }
        }

        float mnew[4], alpha[4], rs[4];
#pragma unroll
        for (int r = 0; r < 4; r++) {
            float mx = fmaxf(fmaxf(s[0][r], s[1][r]), fmaxf(s[2][r], s[3][r]));
            mx = fmaxf(mx, __shfl_xor(mx, 1, 64));
            mx = fmaxf(mx, __shfl_xor(mx, 2, 64));
            mx = fmaxf(mx, __shfl_xor(mx, 4, 64));
            mx = fmaxf(mx, __shfl_xor(mx, 8, 64));
            mnew[r] = fmaxf(mprev[r], mx);
            alpha[r] = __expf(mprev[r] - mnew[r]);
            mprev[r] = mnew[r];
            rs[r] = 0.f;
        }
#pragma unroll
        for (int nt = 0; nt < 4; nt++)
#pragma unroll
            for (int r = 0; r < 4; r++) {
                float p = __expf(s[nt][r] - mnew[r]);
                s[nt][r] = p;
                rs[r] += p;
            }
#pragma unroll
        for (int r = 0; r < 4; r++) {
            rs[r] += __shfl_xor(rs[r], 1, 64);
            rs[r] += __shfl_xor(rs[r], 2, 64);
            rs[r] += __shfl_xor(rs[r], 4, 64);
            rs[r] += __shfl_xor(rs[r], 8, 64);
            lsum[r] = lsum[r] * alpha[r] + rs[r];
        }
#pragma unroll
        for (int i = 0; i < 8; i++)
#pragma unroll
            for (int r = 0; r < 4; r++) o[i][r] *= alpha[r];

        // P: C-layout regs -> LDS -> A-layout frags (wave-local round trip)
#pragma unroll
        for (int nt = 0; nt < 4; nt++)
#pragma unroll
            for (int r = 0; r < 4; r++)
                pw[(lk * 4 + r) * 72 + nt * 16 + lrow] = f2bf(s[nt][r]);
        asm volatile("s_waitcnt lgkmcnt(0)" ::: "memory");

#pragma unroll
        for (int k2 = 0; k2 < 2; k2++) {
            short8 pf = *(const short8*)&pw[lrow * 72 + k2 * 32 + lk * 8];
#pragma unroll
            for (int nt = 0; nt < 8; nt++) {
                int r = nt * 16 + lrow;
                int sl = (k2 * 4 + lk) ^ (r & 7);
                short8 vf = *(const short8*)&Vs[r * 64 + sl * 8];
                o[nt] = MFMA_BF16(pf, vf, o[nt]);
            }
        }
    }

    float inv[4];
#pragma unroll
    for (int r = 0; r < 4; r++) inv[r] = 1.0f / lsum[r];
#pragma unroll
    for (int nt = 0; nt < 8; nt++)
#pragma unroll
        for (int r = 0; r < 4; r++) {
            int tok = q0 + w * 16 + lk * 4 + r;
            size_t off = ((size_t)b * 2048 + tok) * 4096 + h * 128 + nt * 16 + lrow;
            ao[off] = f2bf(o[nt][r] * inv[r]);
        }
}

// ---------------- launcher ----------------
extern "C" void kernel_launch(void* const* d_in, const int* in_sizes, int n_in,
                              void* d_out, int out_size, void* d_ws, size_t ws_size,
                              hipStream_t stream)
{
    (void)in_sizes; (void)n_in; (void)out_size; (void)ws_size;
    const float* hidden = (const float*)d_in[0];
    const float* cosb   = (const float*)d_in[1];
    const float* sinb   = (const float*)d_in[2];
    const float* wq     = (const float*)d_in[3];
    const float* wk     = (const float*)d_in[4];
    const float* wv     = (const float*)d_in[5];
    const float* wo     = (const float*)d_in[6];
    const float* qg     = (const float*)d_in[7];
    const float* kg     = (const float*)d_in[8];

    float* out   = (float*)d_out;                    // (2,2048,2560)
    float* k_out = out + (size_t)2 * 2048 * 2560;    // (2,8,2048,128)
    float* v_out = k_out + (size_t)2 * 8 * 2048 * 128;

    // workspace layout (bf16 elements); total ~166 MB
    u16* hid_b = (u16*)d_ws;                  // 4096x2560
    u16* w_b   = hid_b + 10485760;            // 6144x2560 (wq|wk|wv)
    u16* wo_b  = w_b   + 15728640;            // 2560x4096
    u16* q_b   = wo_b  + 10485760;            // (2,32,2048,128)
    u16* k_b   = q_b   + 16777216;            // (2,8,2048,128)
    u16* vt_b  = k_b   + 4194304;             // (2,8,128,2048)
    u16* qkv_b = vt_b  + 4194304;             // 4096x6144
    u16* ao_b  = hid_b;                       // alias: hid_b dead after QKV GEMM

    cvt_kernel<<<10240, 256, 0, stream>>>(hidden, hid_b, 10485760);
    cvt_kernel<<<10240, 256, 0, stream>>>(wq, w_b, 10485760);
    cvt_kernel<<<2560,  256, 0, stream>>>(wk, w_b + 10485760, 2621440);
    cvt_kernel<<<2560,  256, 0, stream>>>(wv, w_b + 13107200, 2621440);
    cvt_kernel<<<10240, 256, 0, stream>>>(wo, wo_b, 10485760);

    // QKV: M=4096 tokens, N=6144, K=2560 -> bf16 qkv_b
    gemm_bt<true><<<dim3(48, 32), 256, 0, stream>>>(hid_b, w_b, qkv_b,
                                                    2560, 2560, 2560, 6144);
    norm_rope<<<49152, 256, 0, stream>>>(qkv_b, cosb, sinb, qg, kg,
                                         q_b, k_b, vt_b, k_out, v_out);
    attn_kernel<<<dim3(64, 32), 256, 0, stream>>>(q_b, k_b, vt_b, ao_b);
    // out-proj: M=4096, N=2560, K=4096 -> fp32 d_out
    gemm_bt<false><<<dim3(20, 32), 256, 0, stream>>>(ao_b, wo_b, out,
                                                     4096, 4096, 4096, 2560);
}

// Round 2
// 674.929 us; speedup vs baseline: 1.0981x; 1.0981x over previous
//
#include <hip/hip_runtime.h>
#include <stdint.h>

typedef unsigned short u16;
typedef __attribute__((ext_vector_type(8))) short short8;
typedef __attribute__((ext_vector_type(4))) float f32x4;

#define MFMA_BF16(a,b,c) __builtin_amdgcn_mfma_f32_16x16x32_bf16((a),(b),(c),0,0,0)

__device__ __forceinline__ u16 f2bf(float x) {
    uint32_t u = __builtin_bit_cast(uint32_t, x);
    u += 0x7fffu + ((u >> 16) & 1u);   // RNE
    return (u16)(u >> 16);
}
__device__ __forceinline__ float bf2f(u16 u) {
    return __builtin_bit_cast(float, (uint32_t)u << 16);
}
// async global->LDS, 16B per lane; LDS dest = wave-uniform base + lane*16
__device__ __forceinline__ void glds16(const void* g, void* lds) {
    __builtin_amdgcn_global_load_lds((const __attribute__((address_space(1))) void*)g,
                                     (__attribute__((address_space(3))) void*)lds,
                                     16, 0, 0);
}

// ---------------- fp32 -> bf16 convert ----------------
__global__ __launch_bounds__(256) void cvt_kernel(const float* __restrict__ src,
                                                  u16* __restrict__ dst, int n) {
    int i = (blockIdx.x * 256 + threadIdx.x) * 4;
    if (i + 4 <= n) {
        float4 v = *(const float4*)(src + i);
        ushort4 o;
        o.x = f2bf(v.x); o.y = f2bf(v.y); o.z = f2bf(v.z); o.w = f2bf(v.w);
        *(ushort4*)(dst + i) = o;
    }
}

// ---------------- GEMM: C[M,N] = A[M,K] * B[N,K]^T (bf16 in, fp32 acc) ----
// 128x128 tile, BK=32, 4 waves each 64x64. XOR-swizzled LDS (2-way reads).
template<bool BF16_OUT>
__global__ __launch_bounds__(256) void gemm_bt(const u16* __restrict__ A,
                                               const u16* __restrict__ B,
                                               void* __restrict__ Cv,
                                               int K, int lda, int ldb, int ldc)
{
    __shared__ __align__(16) u16 As[128 * 32];
    __shared__ __align__(16) u16 Bs[128 * 32];
    const int t = threadIdx.x;
    const int w = t >> 6, l = t & 63;
    const int m0 = blockIdx.y * 128, n0 = blockIdx.x * 128;
    const int wm = (w & 1) * 64, wn = (w >> 1) * 64;
    const int lrow = l & 15, lk = l >> 4;

    f32x4 acc[4][4];
#pragma unroll
    for (int i = 0; i < 4; i++)
#pragma unroll
        for (int j = 0; j < 4; j++) acc[i][j] = (f32x4){0.f, 0.f, 0.f, 0.f};

    const int c0 = t, c1 = t + 256;
    const int r0 = c0 >> 2, g0 = (c0 & 3) ^ ((r0 >> 1) & 3);
    const int r1 = c1 >> 2, g1 = (c1 & 3) ^ ((r1 >> 1) & 3);
    const u16* Ap0 = A + (size_t)(m0 + r0) * lda + g0 * 8;
    const u16* Ap1 = A + (size_t)(m0 + r1) * lda + g1 * 8;
    const u16* Bp0 = B + (size_t)(n0 + r0) * ldb + g0 * 8;
    const u16* Bp1 = B + (size_t)(n0 + r1) * ldb + g1 * 8;
    char* Asb = (char*)As + w * 1024;
    char* Bsb = (char*)Bs + w * 1024;

    for (int k0 = 0; k0 < K; k0 += 32) {
        __syncthreads();
        glds16(Ap0 + k0, Asb);
        glds16(Ap1 + k0, Asb + 4096);
        glds16(Bp0 + k0, Bsb);
        glds16(Bp1 + k0, Bsb + 4096);
        __syncthreads();
        short8 af[4], bf[4];
#pragma unroll
        for (int mi = 0; mi < 4; mi++) {
            int r = wm + mi * 16 + lrow;
            int sl = lk ^ ((r >> 1) & 3);
            af[mi] = *(const short8*)&As[r * 32 + sl * 8];
        }
#pragma unroll
        for (int ni = 0; ni < 4; ni++) {
            int r = wn + ni * 16 + lrow;
            int sl = lk ^ ((r >> 1) & 3);
            bf[ni] = *(const short8*)&Bs[r * 32 + sl * 8];
        }
#pragma unroll
        for (int mi = 0; mi < 4; mi++)
#pragma unroll
            for (int ni = 0; ni < 4; ni++)
                acc[mi][ni] = MFMA_BF16(af[mi], bf[ni], acc[mi][ni]);
    }

    // C/D layout: col = l&15, row = (l>>4)*4 + reg
#pragma unroll
    for (int mi = 0; mi < 4; mi++) {
#pragma unroll
        for (int r = 0; r < 4; r++) {
            int row = m0 + wm + mi * 16 + lk * 4 + r;
#pragma unroll
            for (int ni = 0; ni < 4; ni++) {
                int col = n0 + wn + ni * 16 + lrow;
                float v = acc[mi][ni][r];
                if (BF16_OUT) ((u16*)Cv)[(size_t)row * ldc + col] = f2bf(v);
                else          ((float*)Cv)[(size_t)row * ldc + col] = v;
            }
        }
    }
}

// ---------------- RMSNorm + RoPE for Q and K only -------------------------
// qkv_b: (4096 tokens, 6144) bf16. hd: 0..31 q, 32..39 k.
// One wave per (token, hd); lane l handles d=l and d=l+64 (RoPE pairing).
__global__ __launch_bounds__(256) void norm_rope_qk(const u16* __restrict__ qkv,
        const float* __restrict__ cosb, const float* __restrict__ sinb,
        const float* __restrict__ qg, const float* __restrict__ kg,
        u16* __restrict__ qb, u16* __restrict__ kb, float* __restrict__ k_out)
{
    const int idx = blockIdx.x * 4 + (threadIdx.x >> 6);
    const int l = threadIdx.x & 63;
    const int tok = idx / 40, hd = idx - tok * 40;
    const int b = tok >> 11, pos = tok & 2047;
    const u16* row = qkv + (size_t)tok * 6144 + hd * 128;
    float x1 = bf2f(row[l]), x2 = bf2f(row[l + 64]);
    float ss = x1 * x1 + x2 * x2;
#pragma unroll
    for (int m = 1; m < 64; m <<= 1) ss += __shfl_xor(ss, m, 64);
    float rn = rsqrtf(ss * (1.0f / 128.0f) + 1e-6f);

    const float* gm = (hd < 32) ? qg : kg;
    float xn1 = x1 * rn * gm[l];
    float xn2 = x2 * rn * gm[l + 64];
    float c1 = cosb[(size_t)tok * 128 + l],      s1 = sinb[(size_t)tok * 128 + l];
    float c2 = cosb[(size_t)tok * 128 + l + 64], s2 = sinb[(size_t)tok * 128 + l + 64];
    float y1 = xn1 * c1 - xn2 * s1;   // rotate_half
    float y2 = xn2 * c2 + xn1 * s2;
    if (hd < 32) {
        const float qs = 0.08838834764831845f;  // 1/sqrt(128) folded into q
        size_t base = (((size_t)b * 32 + hd) * 2048 + pos) * 128;
        qb[base + l]      = f2bf(y1 * qs);
        qb[base + l + 64] = f2bf(y2 * qs);
    } else {
        int kv = hd - 32;
        size_t base = (((size_t)b * 8 + kv) * 2048 + pos) * 128;
        k_out[base + l] = y1; k_out[base + l + 64] = y2;
        kb[base + l] = f2bf(y1); kb[base + l + 64] = f2bf(y2);
    }
}

// ---------------- V pack: fp32 new_v (coalesced) + bf16 V^T (LDS transpose)
// grid (32 pos-blocks, 16 b*kv); block handles 64 pos x 128 d.
__global__ __launch_bounds__(256) void v_pack(const u16* __restrict__ qkv,
        float* __restrict__ v_out, u16* __restrict__ vtb)
{
    __shared__ __align__(16) u16 T[64 * 128];   // [pos][d], d-octets XOR (pos&7)
    const int pb = blockIdx.x, bkv = blockIdx.y;
    const int b = bkv >> 3, kv = bkv & 7;
    const int p0 = pb * 64;
    const int t = threadIdx.x;
    const int pos = t >> 2, ch4 = t & 3;
    const u16* src = qkv + (size_t)(b * 2048 + p0 + pos) * 6144 + (40 + kv) * 128 + ch4 * 32;
    float* vdst = v_out + ((size_t)bkv * 2048 + p0 + pos) * 128 + ch4 * 32;
#pragma unroll
    for (int j = 0; j < 4; j++) {
        short8 x = *(const short8*)(src + j * 8);
        float4 f0, f1;
        f0.x = bf2f(x[0]); f0.y = bf2f(x[1]); f0.z = bf2f(x[2]); f0.w = bf2f(x[3]);
        f1.x = bf2f(x[4]); f1.y = bf2f(x[5]); f1.z = bf2f(x[6]); f1.w = bf2f(x[7]);
        *(float4*)(vdst + j * 8)     = f0;
        *(float4*)(vdst + j * 8 + 4) = f1;
        int slot = (ch4 * 4 + j) ^ (pos & 7);
        *(short8*)&T[pos * 128 + slot * 8] = x;
    }
    __syncthreads();
    const int d = t & 127, ph = t >> 7;   // thread owns 32 pos of one d-row
    u16* obase = vtb + ((size_t)bkv * 128 + d) * 2048 + p0 + ph * 32;
#pragma unroll
    for (int g = 0; g < 4; g++) {
        short8 tv;
#pragma unroll
        for (int jj = 0; jj < 8; jj++) {
            int pp = ph * 32 + g * 8 + jj;
            int slot = (d >> 3) ^ (pp & 7);
            tv[jj] = (short)T[pp * 128 + slot * 8 + (d & 7)];
        }
        *(short8*)(obase + g * 8) = tv;
    }
}

// ---------------- Flash attention (causal, GQA, static-max softmax) -------
// Block: one (b,h), 128-row Q tile; 4 waves x 32 q-rows (2 m-tiles). KV=64.
__global__ __launch_bounds__(256, 3) void attn_kernel(const u16* __restrict__ qb,
        const u16* __restrict__ kb, const u16* __restrict__ vtb,
        u16* __restrict__ ao)
{
    __shared__ __align__(16) u16 Ks[64 * 128];    // (kv,d) swizzled, 16KB
    __shared__ __align__(16) u16 Vs[128 * 64];    // (d,kv) swizzled, 16KB
    __shared__ __align__(16) u16 Ps[4][32 * 72];  // per-wave P, stride 72, 18KB

    const int bh = blockIdx.x;
    const int b = bh >> 5, h = bh & 31;
    const int kvh = h >> 2;
    const int qt = (int)gridDim.y - 1 - (int)blockIdx.y;   // heavy-first
    const int q0 = qt * 128;
    const int t = threadIdx.x, w = t >> 6, l = t & 63;
    const int lrow = l & 15, lk = l >> 4;

    const u16* qbase  = qb  + ((size_t)b * 32 + h)  * 2048 * 128;
    const u16* kbase  = kb  + ((size_t)b * 8 + kvh) * 2048 * 128;
    const u16* vtbase = vtb + ((size_t)b * 8 + kvh) * 128 * 2048;

    short8 qf[2][4];   // q frags for 2 m-tiles, resident all kernel
#pragma unroll
    for (int m = 0; m < 2; m++) {
        const u16* qrow = qbase + (size_t)(q0 + w * 32 + m * 16 + lrow) * 128 + lk * 8;
#pragma unroll
        for (int ks = 0; ks < 4; ks++) qf[m][ks] = *(const short8*)(qrow + ks * 32);
    }

    f32x4 o[2][8];
#pragma unroll
    for (int m = 0; m < 2; m++)
#pragma unroll
        for (int i = 0; i < 8; i++) o[m][i] = (f32x4){0.f, 0.f, 0.f, 0.f};
    float lsum[2][4] = {{0.f,0.f,0.f,0.f},{0.f,0.f,0.f,0.f}};

    int kR[4], kG[4], vR[4], vG[4];
#pragma unroll
    for (int i = 0; i < 4; i++) {
        int c = i * 256 + t;
        kR[i] = c >> 4; kG[i] = (c & 15) ^ (kR[i] & 7);
        vR[i] = c >> 3; vG[i] = (c & 7)  ^ (vR[i] & 7);
    }
    char* Ksb = (char*)Ks + w * 1024;
    char* Vsb = (char*)Vs + w * 1024;
    u16* pw = &Ps[w][0];
    const int wrow_max = q0 + w * 32 + 31;   // last q row this wave owns

    const int nkt = 2 * qt + 2;
    for (int kt = 0; kt < nkt; kt++) {
        const int kv0 = kt * 64;
        __syncthreads();
#pragma unroll
        for (int i = 0; i < 4; i++)
            glds16(kbase + (size_t)(kv0 + kR[i]) * 128 + kG[i] * 8, Ksb + i * 4096);
#pragma unroll
        for (int i = 0; i < 4; i++)
            glds16(vtbase + (size_t)vR[i] * 2048 + kv0 + vG[i] * 8, Vsb + i * 4096);
        __syncthreads();

        if (kv0 > wrow_max) continue;   // fully masked for this wave

        // S = Q K^T (q pre-scaled by 1/sqrt(D)); kf reused across both m-tiles
        f32x4 s[2][4];
#pragma unroll
        for (int m = 0; m < 2; m++)
#pragma unroll
            for (int i = 0; i < 4; i++) s[m][i] = (f32x4){0.f, 0.f, 0.f, 0.f};
#pragma unroll
        for (int ks = 0; ks < 4; ks++) {
#pragma unroll
            for (int nt = 0; nt < 4; nt++) {
                int r = nt * 16 + lrow;
                int sl = (ks * 4 + lk) ^ (r & 7);
                short8 kf = *(const short8*)&Ks[r * 128 + sl * 8];
                s[0][nt] = MFMA_BF16(qf[0][ks], kf, s[0][nt]);
                s[1][nt] = MFMA_BF16(qf[1][ks], kf, s[1][nt]);
            }
        }

        // causal mask (diagonal-adjacent tiles only), exp, partial row sums, P
#pragma unroll
        for (int m = 0; m < 2; m++) {
            const int rowbase = q0 + w * 32 + m * 16;
            if (kv0 + 63 > rowbase) {
#pragma unroll
                for (int nt = 0; nt < 4; nt++) {
                    int cg = kv0 + nt * 16 + lrow;
#pragma unroll
                    for (int r = 0; r < 4; r++)
                        if (cg > rowbase + lk * 4 + r) s[m][nt][r] = -1e30f;
                }
            }
#pragma unroll
            for (int nt = 0; nt < 4; nt++)
#pragma unroll
                for (int r = 0; r < 4; r++) {
                    float p = __expf(s[m][nt][r]);   // static max: none needed
                    s[m][nt][r] = p;
                    lsum[m][r] += p;
                    pw[(m * 16 + lk * 4 + r) * 72 + nt * 16 + lrow] = f2bf(p);
                }
        }
        asm volatile("s_waitcnt lgkmcnt(0)" ::: "memory");

        // O += P V ; vf reused across both m-tiles
#pragma unroll
        for (int k2 = 0; k2 < 2; k2++) {
            short8 pf0 = *(const short8*)&pw[lrow * 72 + k2 * 32 + lk * 8];
            short8 pf1 = *(const short8*)&pw[(16 + lrow) * 72 + k2 * 32 + lk * 8];
#pragma unroll
            for (int nt = 0; nt < 8; nt++) {
                int rr = nt * 16 + lrow;
                int sl = (k2 * 4 + lk) ^ (rr & 7);
                short8 vf = *(const short8*)&Vs[rr * 64 + sl * 8];
                o[0][nt] = MFMA_BF16(pf0, vf, o[0][nt]);
                o[1][nt] = MFMA_BF16(pf1, vf, o[1][nt]);
            }
        }
    }

    // one-time cross-lane row-sum reduce (lanes sharing lk hold same rows)
#pragma unroll
    for (int m = 0; m < 2; m++)
#pragma unroll
        for (int r = 0; r < 4; r++) {
            float v = lsum[m][r];
            v += __shfl_xor(v, 1, 64);
            v += __shfl_xor(v, 2, 64);
            v += __shfl_xor(v, 4, 64);
            v += __shfl_xor(v, 8, 64);
            lsum[m][r] = 1.0f / v;
        }
#pragma unroll
    for (int m = 0; m < 2; m++)
#pragma unroll
        for (int nt = 0; nt < 8; nt++)
#pragma unroll
            for (int r = 0; r < 4; r++) {
                int tok = q0 + w * 32 + m * 16 + lk * 4 + r;
                size_t off = ((size_t)b * 2048 + tok) * 4096 + h * 128 + nt * 16 + lrow;
                ao[off] = f2bf(o[m][nt][r] * lsum[m][r]);
            }
}

// ---------------- launcher ----------------
extern "C" void kernel_launch(void* const* d_in, const int* in_sizes, int n_in,
                              void* d_out, int out_size, void* d_ws, size_t ws_size,
                              hipStream_t stream)
{
    (void)in_sizes; (void)n_in; (void)out_size; (void)ws_size;
    const float* hidden = (const float*)d_in[0];
    const float* cosb   = (const float*)d_in[1];
    const float* sinb   = (const float*)d_in[2];
    const float* wq     = (const float*)d_in[3];
    const float* wk     = (const float*)d_in[4];
    const float* wv     = (const float*)d_in[5];
    const float* wo     = (const float*)d_in[6];
    const float* qg     = (const float*)d_in[7];
    const float* kg     = (const float*)d_in[8];

    float* out   = (float*)d_out;                    // (2,2048,2560)
    float* k_out = out + (size_t)2 * 2048 * 2560;    // (2,8,2048,128)
    float* v_out = k_out + (size_t)2 * 8 * 2048 * 128;

    // workspace layout (bf16 elements)
    u16* hid_b = (u16*)d_ws;                  // 4096x2560
    u16* w_b   = hid_b + 10485760;            // 6144x2560 (wq|wk|wv)
    u16* wo_b  = w_b   + 15728640;            // 2560x4096
    u16* q_b   = wo_b  + 10485760;            // (2,32,2048,128)
    u16* k_b   = q_b   + 16777216;            // (2,8,2048,128)
    u16* vt_b  = k_b   + 4194304;             // (2,8,128,2048)
    u16* qkv_b = vt_b  + 4194304;             // 4096x6144
    u16* ao_b  = hid_b;                       // alias: hid_b+w_b dead after QKV

    cvt_kernel<<<10240, 256, 0, stream>>>(hidden, hid_b, 10485760);
    cvt_kernel<<<10240, 256, 0, stream>>>(wq, w_b, 10485760);
    cvt_kernel<<<2560,  256, 0, stream>>>(wk, w_b + 10485760, 2621440);
    cvt_kernel<<<2560,  256, 0, stream>>>(wv, w_b + 13107200, 2621440);
    cvt_kernel<<<10240, 256, 0, stream>>>(wo, wo_b, 10485760);

    // QKV: M=4096 tokens, N=6144, K=2560 -> bf16 qkv_b
    gemm_bt<true><<<dim3(48, 32), 256, 0, stream>>>(hid_b, w_b, qkv_b,
                                                    2560, 2560, 2560, 6144);
    norm_rope_qk<<<40960, 256, 0, stream>>>(qkv_b, cosb, sinb, qg, kg,
                                            q_b, k_b, k_out);
    v_pack<<<dim3(32, 16), 256, 0, stream>>>(qkv_b, v_out, vt_b);
    attn_kernel<<<dim3(64, 16), 256, 0, stream>>>(q_b, k_b, vt_b, ao_b);
    // out-proj: M=4096, N=2560, K=4096 -> fp32 d_out
    gemm_bt<false><<<dim3(20, 32), 256, 0, stream>>>(ao_b, wo_b, out,
                                                     4096, 4096, 4096, 2560);
}

// Round 3
// 661.804 us; speedup vs baseline: 1.1198x; 1.0198x over previous
//
#include <hip/hip_runtime.h>
#include <stdint.h>

typedef unsigned short u16;
typedef __attribute__((ext_vector_type(8))) short short8;
typedef __attribute__((ext_vector_type(4))) float f32x4;

#define MFMA_BF16(a,b,c) __builtin_amdgcn_mfma_f32_16x16x32_bf16((a),(b),(c),0,0,0)

__device__ __forceinline__ u16 f2bf(float x) {
    uint32_t u = __builtin_bit_cast(uint32_t, x);
    u += 0x7fffu + ((u >> 16) & 1u);   // RNE
    return (u16)(u >> 16);
}
__device__ __forceinline__ float bf2f(u16 u) {
    return __builtin_bit_cast(float, (uint32_t)u << 16);
}
// async global->LDS, 16B per lane; LDS dest = wave-uniform base + lane*16
__device__ __forceinline__ void glds16(const void* g, void* lds) {
    __builtin_amdgcn_global_load_lds((const __attribute__((address_space(1))) void*)g,
                                     (__attribute__((address_space(3))) void*)lds,
                                     16, 0, 0);
}

// ---------------- fused fp32 -> bf16 convert (all 5 tensors, 1 launch) ----
__device__ __forceinline__ void cvt4(const float* __restrict__ s,
                                     u16* __restrict__ d, int i) {
    float4 v = *(const float4*)(s + i);
    ushort4 o;
    o.x = f2bf(v.x); o.y = f2bf(v.y); o.z = f2bf(v.z); o.w = f2bf(v.w);
    *(ushort4*)(d + i) = o;
}
__global__ __launch_bounds__(256) void cvt_all(
        const float* __restrict__ s0, u16* __restrict__ d0,   // hidden 10485760
        const float* __restrict__ s1, u16* __restrict__ d1,   // wq     10485760
        const float* __restrict__ s2, u16* __restrict__ d2,   // wk      2621440
        const float* __restrict__ s3, u16* __restrict__ d3,   // wv      2621440
        const float* __restrict__ s4, u16* __restrict__ d4)   // wo     10485760
{
    int i = (blockIdx.x * 256 + threadIdx.x) * 4;
    if      (i < 10485760) cvt4(s0, d0, i);
    else if (i < 20971520) cvt4(s1, d1, i - 10485760);
    else if (i < 23592960) cvt4(s2, d2, i - 20971520);
    else if (i < 26214400) cvt4(s3, d3, i - 23592960);
    else if (i < 36700160) cvt4(s4, d4, i - 26214400);
}

// ---------------- GEMM: C[M,N] = A[M,K] * B[N,K]^T (bf16 in, fp32 acc) ----
// 128x128 tile, BK=64 (32 MFMA per barrier per wave), 4 waves each 64x64.
// XOR-swizzled LDS; read pattern measures 0 bank conflicts.
template<bool BF16_OUT>
__global__ __launch_bounds__(256) void gemm_bt(const u16* __restrict__ A,
                                               const u16* __restrict__ B,
                                               void* __restrict__ Cv,
                                               int K, int lda, int ldb, int ldc)
{
    __shared__ __align__(16) u16 As[128 * 64];   // 16 KB
    __shared__ __align__(16) u16 Bs[128 * 64];   // 16 KB
    const int t = threadIdx.x;
    const int w = t >> 6, l = t & 63;
    const int m0 = blockIdx.y * 128, n0 = blockIdx.x * 128;
    const int wm = (w & 1) * 64, wn = (w >> 1) * 64;
    const int lrow = l & 15, lk = l >> 4;

    f32x4 acc[4][4];
#pragma unroll
    for (int i = 0; i < 4; i++)
#pragma unroll
        for (int j = 0; j < 4; j++) acc[i][j] = (f32x4){0.f, 0.f, 0.f, 0.f};

    // staging: wave w, iter i covers LDS bytes [w*1024 + i*4096, +1024).
    // row = w*8 + i*32 + (l>>3), slot = l&7; slot s of row r holds chunk
    // g = s ^ (r&7); here r&7 == (l>>3) always.
    const int row_b = w * 8 + (l >> 3);
    const int gsw = ((l & 7) ^ (l >> 3)) * 8;
    const u16* Ap[4]; const u16* Bp[4];
#pragma unroll
    for (int i = 0; i < 4; i++) {
        Ap[i] = A + (size_t)(m0 + row_b + i * 32) * lda + gsw;
        Bp[i] = B + (size_t)(n0 + row_b + i * 32) * ldb + gsw;
    }
    char* Asb = (char*)As + w * 1024;
    char* Bsb = (char*)Bs + w * 1024;

    for (int k0 = 0; k0 < K; k0 += 64) {
        __syncthreads();
#pragma unroll
        for (int i = 0; i < 4; i++) glds16(Ap[i] + k0, Asb + i * 4096);
#pragma unroll
        for (int i = 0; i < 4; i++) glds16(Bp[i] + k0, Bsb + i * 4096);
        __syncthreads();
#pragma unroll
        for (int k2 = 0; k2 < 2; k2++) {
            const int slb = (k2 * 4 + lk) ^ (lrow & 7);
            short8 af[4], bf[4];
#pragma unroll
            for (int mi = 0; mi < 4; mi++)
                af[mi] = *(const short8*)&As[(wm + mi * 16 + lrow) * 64 + slb * 8];
#pragma unroll
            for (int ni = 0; ni < 4; ni++)
                bf[ni] = *(const short8*)&Bs[(wn + ni * 16 + lrow) * 64 + slb * 8];
#pragma unroll
            for (int mi = 0; mi < 4; mi++)
#pragma unroll
                for (int ni = 0; ni < 4; ni++)
                    acc[mi][ni] = MFMA_BF16(af[mi], bf[ni], acc[mi][ni]);
        }
    }

    // C/D layout: col = l&15, row = (l>>4)*4 + reg
#pragma unroll
    for (int mi = 0; mi < 4; mi++) {
#pragma unroll
        for (int r = 0; r < 4; r++) {
            int row = m0 + wm + mi * 16 + lk * 4 + r;
#pragma unroll
            for (int ni = 0; ni < 4; ni++) {
                int col = n0 + wn + ni * 16 + lrow;
                float v = acc[mi][ni][r];
                if (BF16_OUT) ((u16*)Cv)[(size_t)row * ldc + col] = f2bf(v);
                else          ((float*)Cv)[(size_t)row * ldc + col] = v;
            }
        }
    }
}

// ---------------- RMSNorm + RoPE for Q and K only -------------------------
// qkv_b: (4096 tokens, 6144) bf16. hd: 0..31 q, 32..39 k.
// One wave per (token, hd); lane l handles d=l and d=l+64 (RoPE pairing).
__global__ __launch_bounds__(256) void norm_rope_qk(const u16* __restrict__ qkv,
        const float* __restrict__ cosb, const float* __restrict__ sinb,
        const float* __restrict__ qg, const float* __restrict__ kg,
        u16* __restrict__ qb, u16* __restrict__ kb, float* __restrict__ k_out)
{
    const int idx = blockIdx.x * 4 + (threadIdx.x >> 6);
    const int l = threadIdx.x & 63;
    const int tok = idx / 40, hd = idx - tok * 40;
    const int b = tok >> 11, pos = tok & 2047;
    const u16* row = qkv + (size_t)tok * 6144 + hd * 128;
    float x1 = bf2f(row[l]), x2 = bf2f(row[l + 64]);
    float ss = x1 * x1 + x2 * x2;
#pragma unroll
    for (int m = 1; m < 64; m <<= 1) ss += __shfl_xor(ss, m, 64);
    float rn = rsqrtf(ss * (1.0f / 128.0f) + 1e-6f);

    const float* gm = (hd < 32) ? qg : kg;
    float xn1 = x1 * rn * gm[l];
    float xn2 = x2 * rn * gm[l + 64];
    float c1 = cosb[(size_t)tok * 128 + l],      s1 = sinb[(size_t)tok * 128 + l];
    float c2 = cosb[(size_t)tok * 128 + l + 64], s2 = sinb[(size_t)tok * 128 + l + 64];
    float y1 = xn1 * c1 - xn2 * s1;   // rotate_half
    float y2 = xn2 * c2 + xn1 * s2;
    if (hd < 32) {
        const float qs = 0.08838834764831845f;  // 1/sqrt(128) folded into q
        size_t base = (((size_t)b * 32 + hd) * 2048 + pos) * 128;
        qb[base + l]      = f2bf(y1 * qs);
        qb[base + l + 64] = f2bf(y2 * qs);
    } else {
        int kv = hd - 32;
        size_t base = (((size_t)b * 8 + kv) * 2048 + pos) * 128;
        k_out[base + l] = y1; k_out[base + l + 64] = y2;
        kb[base + l] = f2bf(y1); kb[base + l + 64] = f2bf(y2);
    }
}

// ---------------- V pack: fp32 new_v (coalesced) + bf16 V^T (LDS transpose)
// grid (32 pos-blocks, 16 b*kv); block handles 64 pos x 128 d.
__global__ __launch_bounds__(256) void v_pack(const u16* __restrict__ qkv,
        float* __restrict__ v_out, u16* __restrict__ vtb)
{
    __shared__ __align__(16) u16 T[64 * 128];   // [pos][d], d-octets XOR (pos&7)
    const int pb = blockIdx.x, bkv = blockIdx.y;
    const int b = bkv >> 3, kv = bkv & 7;
    const int p0 = pb * 64;
    const int t = threadIdx.x;
    const int pos = t >> 2, ch4 = t & 3;
    const u16* src = qkv + (size_t)(b * 2048 + p0 + pos) * 6144 + (40 + kv) * 128 + ch4 * 32;
    float* vdst = v_out + ((size_t)bkv * 2048 + p0 + pos) * 128 + ch4 * 32;
#pragma unroll
    for (int j = 0; j < 4; j++) {
        short8 x = *(const short8*)(src + j * 8);
        float4 f0, f1;
        f0.x = bf2f(x[0]); f0.y = bf2f(x[1]); f0.z = bf2f(x[2]); f0.w = bf2f(x[3]);
        f1.x = bf2f(x[4]); f1.y = bf2f(x[5]); f1.z = bf2f(x[6]); f1.w = bf2f(x[7]);
        *(float4*)(vdst + j * 8)     = f0;
        *(float4*)(vdst + j * 8 + 4) = f1;
        int slot = (ch4 * 4 + j) ^ (pos & 7);
        *(short8*)&T[pos * 128 + slot * 8] = x;
    }
    __syncthreads();
    const int d = t & 127, ph = t >> 7;   // thread owns 32 pos of one d-row
    u16* obase = vtb + ((size_t)bkv * 128 + d) * 2048 + p0 + ph * 32;
#pragma unroll
    for (int g = 0; g < 4; g++) {
        short8 tv;
#pragma unroll
        for (int jj = 0; jj < 8; jj++) {
            int pp = ph * 32 + g * 8 + jj;
            int slot = (d >> 3) ^ (pp & 7);
            tv[jj] = (short)T[pp * 128 + slot * 8 + (d & 7)];
        }
        *(short8*)(obase + g * 8) = tv;
    }
}

// ---------------- Flash attention (causal, GQA, static-max softmax) -------
// Block: one (b,h), 128-row Q tile; 4 waves x 32 q-rows (2 m-tiles). KV=64.
__global__ __launch_bounds__(256, 3) void attn_kernel(const u16* __restrict__ qb,
        const u16* __restrict__ kb, const u16* __restrict__ vtb,
        u16* __restrict__ ao)
{
    __shared__ __align__(16) u16 Ks[64 * 128];    // (kv,d) swizzled, 16KB
    __shared__ __align__(16) u16 Vs[128 * 64];    // (d,kv) swizzled, 16KB
    __shared__ __align__(16) u16 Ps[4][32 * 72];  // per-wave P, stride 72, 18KB

    const int bh = blockIdx.x;
    const int b = bh >> 5, h = bh & 31;
    const int kvh = h >> 2;
    const int qt = (int)gridDim.y - 1 - (int)blockIdx.y;   // heavy-first
    const int q0 = qt * 128;
    const int t = threadIdx.x, w = t >> 6, l = t & 63;
    const int lrow = l & 15, lk = l >> 4;

    const u16* qbase  = qb  + ((size_t)b * 32 + h)  * 2048 * 128;
    const u16* kbase  = kb  + ((size_t)b * 8 + kvh) * 2048 * 128;
    const u16* vtbase = vtb + ((size_t)b * 8 + kvh) * 128 * 2048;

    short8 qf[2][4];   // q frags for 2 m-tiles, resident all kernel
#pragma unroll
    for (int m = 0; m < 2; m++) {
        const u16* qrow = qbase + (size_t)(q0 + w * 32 + m * 16 + lrow) * 128 + lk * 8;
#pragma unroll
        for (int ks = 0; ks < 4; ks++) qf[m][ks] = *(const short8*)(qrow + ks * 32);
    }

    f32x4 o[2][8];
#pragma unroll
    for (int m = 0; m < 2; m++)
#pragma unroll
        for (int i = 0; i < 8; i++) o[m][i] = (f32x4){0.f, 0.f, 0.f, 0.f};
    float lsum[2][4] = {{0.f,0.f,0.f,0.f},{0.f,0.f,0.f,0.f}};

    int kR[4], kG[4], vR[4], vG[4];
#pragma unroll
    for (int i = 0; i < 4; i++) {
        int c = i * 256 + t;
        kR[i] = c >> 4; kG[i] = (c & 15) ^ (kR[i] & 7);
        vR[i] = c >> 3; vG[i] = (c & 7)  ^ (vR[i] & 7);
    }
    char* Ksb = (char*)Ks + w * 1024;
    char* Vsb = (char*)Vs + w * 1024;
    u16* pw = &Ps[w][0];
    const int wrow_max = q0 + w * 32 + 31;   // last q row this wave owns

    const int nkt = 2 * qt + 2;
    for (int kt = 0; kt < nkt; kt++) {
        const int kv0 = kt * 64;
        __syncthreads();
#pragma unroll
        for (int i = 0; i < 4; i++)
            glds16(kbase + (size_t)(kv0 + kR[i]) * 128 + kG[i] * 8, Ksb + i * 4096);
#pragma unroll
        for (int i = 0; i < 4; i++)
            glds16(vtbase + (size_t)vR[i] * 2048 + kv0 + vG[i] * 8, Vsb + i * 4096);
        __syncthreads();

        if (kv0 > wrow_max) continue;   // fully masked for this wave

        // S = Q K^T (q pre-scaled by 1/sqrt(D)); kf reused across both m-tiles
        f32x4 s[2][4];
#pragma unroll
        for (int m = 0; m < 2; m++)
#pragma unroll
            for (int i = 0; i < 4; i++) s[m][i] = (f32x4){0.f, 0.f, 0.f, 0.f};
#pragma unroll
        for (int ks = 0; ks < 4; ks++) {
#pragma unroll
            for (int nt = 0; nt < 4; nt++) {
                int r = nt * 16 + lrow;
                int sl = (ks * 4 + lk) ^ (r & 7);
                short8 kf = *(const short8*)&Ks[r * 128 + sl * 8];
                s[0][nt] = MFMA_BF16(qf[0][ks], kf, s[0][nt]);
                s[1][nt] = MFMA_BF16(qf[1][ks], kf, s[1][nt]);
            }
        }

        // causal mask (diagonal-adjacent tiles only), exp, partial row sums, P
#pragma unroll
        for (int m = 0; m < 2; m++) {
            const int rowbase = q0 + w * 32 + m * 16;
            if (kv0 + 63 > rowbase) {
#pragma unroll
                for (int nt = 0; nt < 4; nt++) {
                    int cg = kv0 + nt * 16 + lrow;
#pragma unroll
                    for (int r = 0; r < 4; r++)
                        if (cg > rowbase + lk * 4 + r) s[m][nt][r] = -1e30f;
                }
            }
#pragma unroll
            for (int nt = 0; nt < 4; nt++)
#pragma unroll
                for (int r = 0; r < 4; r++) {
                    float p = __expf(s[m][nt][r]);   // static max: none needed
                    s[m][nt][r] = p;
                    lsum[m][r] += p;
                    pw[(m * 16 + lk * 4 + r) * 72 + nt * 16 + lrow] = f2bf(p);
                }
        }
        asm volatile("s_waitcnt lgkmcnt(0)" ::: "memory");

        // O += P V ; vf reused across both m-tiles
#pragma unroll
        for (int k2 = 0; k2 < 2; k2++) {
            short8 pf0 = *(const short8*)&pw[lrow * 72 + k2 * 32 + lk * 8];
            short8 pf1 = *(const short8*)&pw[(16 + lrow) * 72 + k2 * 32 + lk * 8];
#pragma unroll
            for (int nt = 0; nt < 8; nt++) {
                int rr = nt * 16 + lrow;
                int sl = (k2 * 4 + lk) ^ (rr & 7);
                short8 vf = *(const short8*)&Vs[rr * 64 + sl * 8];
                o[0][nt] = MFMA_BF16(pf0, vf, o[0][nt]);
                o[1][nt] = MFMA_BF16(pf1, vf, o[1][nt]);
            }
        }
    }

    // one-time cross-lane row-sum reduce (lanes sharing lk hold same rows)
#pragma unroll
    for (int m = 0; m < 2; m++)
#pragma unroll
        for (int r = 0; r < 4; r++) {
            float v = lsum[m][r];
            v += __shfl_xor(v, 1, 64);
            v += __shfl_xor(v, 2, 64);
            v += __shfl_xor(v, 4, 64);
            v += __shfl_xor(v, 8, 64);
            lsum[m][r] = 1.0f / v;
        }
#pragma unroll
    for (int m = 0; m < 2; m++)
#pragma unroll
        for (int nt = 0; nt < 8; nt++)
#pragma unroll
            for (int r = 0; r < 4; r++) {
                int tok = q0 + w * 32 + m * 16 + lk * 4 + r;
                size_t off = ((size_t)b * 2048 + tok) * 4096 + h * 128 + nt * 16 + lrow;
                ao[off] = f2bf(o[m][nt][r] * lsum[m][r]);
            }
}

// ---------------- launcher ----------------
extern "C" void kernel_launch(void* const* d_in, const int* in_sizes, int n_in,
                              void* d_out, int out_size, void* d_ws, size_t ws_size,
                              hipStream_t stream)
{
    (void)in_sizes; (void)n_in; (void)out_size; (void)ws_size;
    const float* hidden = (const float*)d_in[0];
    const float* cosb   = (const float*)d_in[1];
    const float* sinb   = (const float*)d_in[2];
    const float* wq     = (const float*)d_in[3];
    const float* wk     = (const float*)d_in[4];
    const float* wv     = (const float*)d_in[5];
    const float* wo     = (const float*)d_in[6];
    const float* qg     = (const float*)d_in[7];
    const float* kg     = (const float*)d_in[8];

    float* out   = (float*)d_out;                    // (2,2048,2560)
    float* k_out = out + (size_t)2 * 2048 * 2560;    // (2,8,2048,128)
    float* v_out = k_out + (size_t)2 * 8 * 2048 * 128;

    // workspace layout (bf16 elements)
    u16* hid_b = (u16*)d_ws;                  // 4096x2560
    u16* w_b   = hid_b + 10485760;            // 6144x2560 (wq|wk|wv)
    u16* wo_b  = w_b   + 15728640;            // 2560x4096
    u16* q_b   = wo_b  + 10485760;            // (2,32,2048,128)
    u16* k_b   = q_b   + 16777216;            // (2,8,2048,128)
    u16* vt_b  = k_b   + 4194304;             // (2,8,128,2048)
    u16* qkv_b = vt_b  + 4194304;             // 4096x6144
    u16* ao_b  = hid_b;                       // alias: hid_b+w_b dead after QKV

    cvt_all<<<35840, 256, 0, stream>>>(hidden, hid_b, wq, w_b,
                                       wk, w_b + 10485760, wv, w_b + 13107200,
                                       wo, wo_b);

    // QKV: M=4096 tokens, N=6144, K=2560 -> bf16 qkv_b
    gemm_bt<true><<<dim3(48, 32), 256, 0, stream>>>(hid_b, w_b, qkv_b,
                                                    2560, 2560, 2560, 6144);
    norm_rope_qk<<<40960, 256, 0, stream>>>(qkv_b, cosb, sinb, qg, kg,
                                            q_b, k_b, k_out);
    v_pack<<<dim3(32, 16), 256, 0, stream>>>(qkv_b, v_out, vt_b);
    attn_kernel<<<dim3(64, 16), 256, 0, stream>>>(q_b, k_b, vt_b, ao_b);
    // out-proj: M=4096, N=2560, K=4096 -> fp32 d_out
    gemm_bt<false><<<dim3(20, 32), 256, 0, stream>>>(ao_b, wo_b, out,
                                                     4096, 4096, 4096, 2560);
}